// Round 1
// 398.971 us; speedup vs baseline: 1.0748x; 1.0748x over previous
//
#include <hip/hip_runtime.h>
#include <hip/hip_bf16.h>
#include <stdint.h>

#define N_TOK 8192
#define DIM   1024
#define HID   2048
#define NEXP  8
#define RB    256   // route blocks (32 tokens each)

typedef __bf16 bf16x8 __attribute__((ext_vector_type(8)));
typedef float  f32x4  __attribute__((ext_vector_type(4)));
typedef unsigned short u16x8 __attribute__((ext_vector_type(8)));
typedef unsigned short u16x4 __attribute__((ext_vector_type(4)));

__device__ __forceinline__ float bits2f(unsigned short u) {
    union { unsigned int i; float f; } c; c.i = ((unsigned int)u) << 16; return c.f;
}
__device__ __forceinline__ unsigned short f2bfbits(float f) {
    __hip_bfloat16 h = __float2bfloat16(f);
    return *(unsigned short*)&h;
}

// ---- async global->LDS, 16B per lane ----
__device__ __forceinline__ void load_lds16(const void* g, void* l) {
    __builtin_amdgcn_global_load_lds(
        (const __attribute__((address_space(1))) void*)g,
        (__attribute__((address_space(3))) void*)l,
        16, 0, 0);
}

// ======================= phase 1: route + weight transpose/convert (fused) ==========
// blockIdx.x < RB           : route (32 tokens/block, 256 thr)
// next 4096 blocks          : w1 transpose+cvt  (R=DIM rows, C=HID cols, 64x64 tiles)
// next 4096 blocks          : w2 transpose+cvt  (R=HID, C=DIM)
__global__ __launch_bounds__(256) void fused_pre_k(
    const float* __restrict__ x,
    const float* __restrict__ gate,
    const float* __restrict__ w1,
    const float* __restrict__ w2,
    int* __restrict__ epack, float* __restrict__ pw,
    unsigned short* __restrict__ xb,
    int* __restrict__ H0, int* __restrict__ H1, float* __restrict__ Pblk,
    unsigned short* __restrict__ w1t, unsigned short* __restrict__ w2t)
{
    __shared__ __align__(16) union {
        struct { float gw[NEXP][16][64]; int h0[NEXP]; int h1[NEXP]; float p[NEXP]; } r;
        unsigned short tile[64][72];
    } S;
    const int tid = threadIdx.x;
    const int bx  = blockIdx.x;

    if (bx < RB) {
        // ------------- route -------------
        if (tid < NEXP) { S.r.h0[tid] = 0; S.r.h1[tid] = 0; S.r.p[tid] = 0.f; }
        for (int idx = tid; idx < NEXP * DIM; idx += 256) {
            int e = idx >> 10, rem = idx & 1023, i = rem >> 6, l = rem & 63;
            S.r.gw[e][i][l] = gate[e * DIM + l * 16 + i];
        }
        __syncthreads();
        int w = tid >> 6, lane = tid & 63;
        float prAcc[NEXP];
        #pragma unroll
        for (int e = 0; e < NEXP; ++e) prAcc[e] = 0.f;
        for (int it = 0; it < 8; ++it) {
            int token = bx * 32 + w * 8 + it;
            const float* xr = x + (size_t)token * DIM + lane * 16;
            float xv[16];
            #pragma unroll
            for (int q = 0; q < 4; ++q) {
                float4 v = *(const float4*)(xr + q * 4);
                xv[q * 4 + 0] = v.x; xv[q * 4 + 1] = v.y; xv[q * 4 + 2] = v.z; xv[q * 4 + 3] = v.w;
            }
            {
                u16x8 o0, o1;
                #pragma unroll
                for (int i = 0; i < 8; ++i) { o0[i] = f2bfbits(xv[i]); o1[i] = f2bfbits(xv[8 + i]); }
                unsigned short* dst = xb + (size_t)token * DIM + lane * 16;
                *(u16x8*)dst = o0;
                *(u16x8*)(dst + 8) = o1;
            }
            float lg[NEXP];
            #pragma unroll
            for (int e = 0; e < NEXP; ++e) {
                float s = 0.f;
                #pragma unroll
                for (int i = 0; i < 16; ++i) s += xv[i] * S.r.gw[e][i][lane];
                lg[e] = s;
            }
            #pragma unroll
            for (int off = 32; off > 0; off >>= 1)
                #pragma unroll
                for (int e = 0; e < NEXP; ++e) lg[e] += __shfl_xor(lg[e], off);
            float mx = lg[0]; int am = 0;
            #pragma unroll
            for (int e = 1; e < NEXP; ++e) if (lg[e] > mx) { mx = lg[e]; am = e; }
            float pr[NEXP], se = 0.f;
            #pragma unroll
            for (int e = 0; e < NEXP; ++e) { pr[e] = __expf(lg[e] - mx); se += pr[e]; }
            float inv = 1.f / se;
            #pragma unroll
            for (int e = 0; e < NEXP; ++e) pr[e] *= inv;
            float m2 = -1.f; int a2 = 0;
            #pragma unroll
            for (int e = 0; e < NEXP; ++e) if (e != am && pr[e] > m2) { m2 = pr[e]; a2 = e; }
            float psum = pr[am] + m2;
            if (lane == 0) {
                epack[token] = am | (a2 << 4);
                pw[token * 2] = pr[am] / psum;
                pw[token * 2 + 1] = m2 / psum;
                atomicAdd(&S.r.h0[am], 1);
                atomicAdd(&S.r.h1[a2], 1);
                #pragma unroll
                for (int e = 0; e < NEXP; ++e) prAcc[e] += pr[e];
            }
        }
        if (lane == 0) {
            #pragma unroll
            for (int e = 0; e < NEXP; ++e) atomicAdd(&S.r.p[e], prAcc[e]);
        }
        __syncthreads();
        if (tid < NEXP) {
            H0[bx * NEXP + tid] = S.r.h0[tid];
            H1[bx * NEXP + tid] = S.r.h1[tid];
            Pblk[bx * NEXP + tid] = S.r.p[tid];
        }
        return;
    }

    // ------------- transpose + fp32->bf16 -------------
    int bT = bx - RB;
    const float* inp; unsigned short* outp;
    int R, C, r0, c0;
    if (bT < 4096) {                    // w1: R=1024 rows, C=2048 cols -> 16 x 32 tiles
        int e = bT >> 9, rem = bT & 511;
        R = DIM; C = HID;
        inp = w1 + (size_t)e * R * C; outp = w1t + (size_t)e * R * C;
        r0 = (rem >> 5) << 6; c0 = (rem & 31) << 6;
    } else {                            // w2: R=2048 rows, C=1024 cols -> 32 x 16 tiles
        int b2 = bT - 4096;
        int e = b2 >> 9, rem = b2 & 511;
        R = HID; C = DIM;
        inp = w2 + (size_t)e * R * C; outp = w2t + (size_t)e * R * C;
        r0 = (rem >> 4) << 6; c0 = (rem & 15) << 6;
    }
    {
        int r = tid >> 2, cseg = (tid & 3) * 16;
        const float* src = inp + (size_t)(r0 + r) * C + c0 + cseg;
        #pragma unroll
        for (int q = 0; q < 4; ++q) {
            float4 v = *(const float4*)(src + q * 4);
            S.tile[r][cseg + q * 4 + 0] = f2bfbits(v.x);
            S.tile[r][cseg + q * 4 + 1] = f2bfbits(v.y);
            S.tile[r][cseg + q * 4 + 2] = f2bfbits(v.z);
            S.tile[r][cseg + q * 4 + 3] = f2bfbits(v.w);
        }
    }
    __syncthreads();
    {
        int c = tid >> 2, rseg = (tid & 3) * 16;
        unsigned short* dst = outp + (size_t)(c0 + c) * R + r0 + rseg;
        #pragma unroll
        for (int h = 0; h < 2; ++h) {
            u16x8 o;
            #pragma unroll
            for (int i = 0; i < 8; ++i) o[i] = S.tile[rseg + h * 8 + i][c];
            *(u16x8*)(dst + h * 8) = o;
        }
    }
}

// ======================= phase 2: scan (1 block) =======================
__global__ __launch_bounds__(256) void scan_k(
    const int* __restrict__ H0, const int* __restrict__ H1,
    const float* __restrict__ Pblk,
    int* __restrict__ bbL, int* __restrict__ counts, int* __restrict__ basep,
    float* __restrict__ aux)
{
    __shared__ int h0S[RB * NEXP], h1S[RB * NEXP], bbS[RB * NEXP];
    __shared__ float pSh[RB * NEXP];
    __shared__ int cS[NEXP], fS[NEXP];
    __shared__ float psS[NEXP];
    int tid = threadIdx.x;
    for (int i = tid; i < RB * NEXP; i += 256) { h0S[i] = H0[i]; h1S[i] = H1[i]; pSh[i] = Pblk[i]; }
    __syncthreads();
    if (tid < NEXP) {
        int run = 0, f = 0; float p = 0.f;
        for (int b = 0; b < RB; ++b) {
            int i = b * NEXP + tid;
            bbS[i] = run;
            run += h0S[i] + h1S[i];
            f += h0S[i];
            p += pSh[i];
        }
        cS[tid] = run; fS[tid] = f; psS[tid] = p;
        counts[tid] = run;
    }
    __syncthreads();
    if (tid == 0) {
        int b = 0; float s = 0.f;
        for (int e = 0; e < NEXP; ++e) {
            basep[e] = b; b += cS[e];
            s += (fS[e] * (1.f / 8192.f)) * (psS[e] * (1.f / 8192.f));
        }
        aux[0] = 0.01f * 8.f * s;
    }
    __syncthreads();
    for (int i = tid; i < RB * NEXP; i += 256) bbL[i] = bbS[i];
}

// ======================= phase 3: scatter (ballot ranking, no atomics) ==============
__global__ __launch_bounds__(256) void scatter_k(
    const int* __restrict__ epack, const int* __restrict__ bbL,
    int* __restrict__ tok_list, int* __restrict__ code)
{
    int tid = threadIdx.x;
    int w = tid >> 6, lane = tid & 63;
    int g = blockIdx.x * 4 + w;
    int token = g * 32 + (lane >> 1);
    int ep = epack[token];
    int e = (lane & 1) ? ((ep >> 4) & 0xF) : (ep & 0xF);
    unsigned long long lower = (lane == 0) ? 0ull : ((~0ull) >> (64 - lane));
    unsigned long long mymask = 0;
    #pragma unroll
    for (int ee = 0; ee < NEXP; ++ee) {
        unsigned long long m = __ballot(e == ee);
        if (ee == e) mymask = m;
    }
    int rank = __popcll(mymask & lower);
    int slot = bbL[g * NEXP + e] + rank;
    tok_list[e * N_TOK + slot] = token;
    code[token * 2 + (lane & 1)] = (e << 13) | slot;
}

// ======================= grouped MFMA GEMM: deep-prefetch counted-vmcnt pipeline =====
// Tile 128x128, BK=64 (two 32-k halves per tile), double-buffered 64 KB LDS.
// LDS (ushort units), buffer b at b*16384:
//   Ak0 [0,4096) Ak1 [4096,8192) Bk0 [8192,12288) Bk1 [12288,16384)
//   half layout: row r (0..127) stride 32, chunk pos c in 0..3 holds GLOBAL chunk
//   c ^ ((r>>1)&3)  (stage pre-swizzles the global address; ds_read applies same XOR)
// Stage stream (groups of 4 load_lds instrs = {A,B} halves of one k-half):
//   prologue: g0=k0[0], g1=k1[0], g2=k0[1]
//   even phase of tile t (consumes k0[t]): stages k1[t+1] (group 2t+3)
//   odd  phase of tile t (consumes k1[t]): stages k0[t+2] (group 2t+4)
// Ledger: at even phase need group 2t done -> allow 3 newer groups -> vmcnt(12);
//         at odd  phase need group 2t+1    -> allow 3 newer groups -> vmcnt(12);
//         tail drains 12 -> 8 -> 4 -> 0. vmcnt never 0 in the main loop (T4).
// Every overwritten LDS region's last reader completed before the preceding
// end-of-phase s_barrier (compiler lgkmcnt before MFMA ensures reads retired).
#define VMW(Nv) asm volatile("s_waitcnt vmcnt(" #Nv ")" ::: "memory")
#define BARv()  asm volatile("s_barrier" ::: "memory")

template<bool GATHER, bool RELU, int KT>
__global__ __launch_bounds__(256, 2) void moe_gemm(
    const unsigned short* __restrict__ A,
    const unsigned short* __restrict__ B,
    unsigned short* __restrict__ O,
    const int* __restrict__ counts,
    const int* __restrict__ basep,
    const int* __restrict__ tok_list,
    const int N)
{
    constexpr int K = KT * 64;
    const int e = blockIdx.z;
    const int cnt = counts[e];
    const int m0 = blockIdx.y * 128;
    if (m0 >= cnt) return;
    const int n0 = blockIdx.x * 128;
    const int bas = basep[e];

    const int tid = threadIdx.x;
    const int w = tid >> 6, lane = tid & 63;
    const int wr = w >> 1, wc = w & 1;

    __shared__ __align__(16) unsigned short lds[32768];   // 64 KB -> 2 blocks/CU

    const int kc = ((tid & 3) ^ ((tid >> 3) & 3)) * 8;    // swizzled global chunk in k-half
    const int r0i = tid >> 2, r1i = 64 + (tid >> 2);
    const unsigned short *aRow0, *aRow1;
    if (GATHER) {
        int s0 = m0 + r0i, s1 = m0 + r1i;
        int t0 = (s0 < cnt) ? tok_list[e * N_TOK + s0] : 0;
        int t1 = (s1 < cnt) ? tok_list[e * N_TOK + s1] : 0;
        aRow0 = A + (size_t)t0 * K + kc;
        aRow1 = A + (size_t)t1 * K + kc;
    } else {
        int s0 = m0 + r0i; if (s0 > cnt - 1) s0 = cnt - 1;
        int s1 = m0 + r1i; if (s1 > cnt - 1) s1 = cnt - 1;
        aRow0 = A + (size_t)(bas + s0) * K + kc;
        aRow1 = A + (size_t)(bas + s1) * K + kc;
    }
    const unsigned short* Be = B + (size_t)e * N * K;
    const unsigned short* bRow0 = Be + (size_t)(n0 + r0i) * K + kc;
    const unsigned short* bRow1 = Be + (size_t)(n0 + r1i) * K + kc;

    f32x4 acc[4][4];
    #pragma unroll
    for (int i = 0; i < 4; ++i)
        #pragma unroll
        for (int j = 0; j < 4; ++j) acc[i][j] = f32x4{0.f, 0.f, 0.f, 0.f};

    const int quad = lane >> 4, ml = lane & 15;
    int offA[4], offB[4];
    #pragma unroll
    for (int i = 0; i < 4; ++i) {
        int Ra = wr * 64 + i * 16 + ml;
        offA[i] = Ra * 32 + ((quad ^ ((Ra >> 1) & 3)) * 8);
        int Rb = wc * 64 + i * 16 + ml;
        offB[i] = Rb * 32 + ((quad ^ ((Rb >> 1) & 3)) * 8);
    }

    // stage one {A,B} half-pair for (tile tt, k-half h): 4 global_load_lds
    auto stageG = [&](int tt, int h) {
        const int db = ((tt & 1) << 14) + (h << 12) + (tid << 3);
        const int toff = tt * 64 + h * 32;
        load_lds16(aRow0 + toff, &lds[db]);
        load_lds16(aRow1 + toff, &lds[db + 2048]);
        load_lds16(bRow0 + toff, &lds[db + 8192]);
        load_lds16(bRow1 + toff, &lds[db + 8192 + 2048]);
    };

    // one compute phase: 8 ds_read_b128 + 16 MFMA + end-of-phase barrier
    auto compute = [&](int bb, int ks) {
        const unsigned short* Lb = &lds[(bb << 14) + (ks << 12)];
        bf16x8 af[4], bfr[4];
        #pragma unroll
        for (int i = 0; i < 4; ++i) af[i] = *(const bf16x8*)&Lb[offA[i]];
        #pragma unroll
        for (int j = 0; j < 4; ++j) bfr[j] = *(const bf16x8*)&Lb[8192 + offB[j]];
        __builtin_amdgcn_s_setprio(1);
        #pragma unroll
        for (int i = 0; i < 4; ++i)
            #pragma unroll
            for (int j = 0; j < 4; ++j)
                acc[i][j] = __builtin_amdgcn_mfma_f32_16x16x32_bf16(af[i], bfr[j], acc[i][j], 0, 0, 0);
        __builtin_amdgcn_s_setprio(0);
        BARv();
    };

    // prologue: 3 groups (12 loads) in flight before first wait
    stageG(0, 0); stageG(0, 1); stageG(1, 0);

    #pragma unroll 2
    for (int t = 0; t < KT - 2; ++t) {
        const int b = t & 1;
        stageG(t + 1, 1); VMW(12); BARv(); compute(b, 0);
        stageG(t + 2, 0); VMW(12); BARv(); compute(b, 1);
    }
    {
        const int bA = (KT - 2) & 1;
        stageG(KT - 1, 1); VMW(12); BARv(); compute(bA, 0);
        VMW(8);  BARv(); compute(bA, 1);
        const int bB = (KT - 1) & 1;
        VMW(4);  BARv(); compute(bB, 0);
        VMW(0);  BARv(); compute(bB, 1);
    }

    #pragma unroll
    for (int i = 0; i < 4; ++i) {
        int rbase = wr * 64 + i * 16 + quad * 4;
        #pragma unroll
        for (int r = 0; r < 4; ++r) {
            int slot = m0 + rbase + r;
            if (slot < cnt) {
                unsigned short* orow = O + (size_t)(bas + slot) * N + n0 + wc * 64 + ml;
                #pragma unroll
                for (int j = 0; j < 4; ++j) {
                    float v = acc[i][j][r];
                    if (RELU) v = v > 0.f ? v : 0.f;
                    orow[j * 16] = f2bfbits(v);
                }
            }
        }
    }
}

// ======================= combine: out[t] = p0*Y[r0] + p1*Y[r1] ===========
__global__ __launch_bounds__(256) void combine_k(
    const unsigned short* __restrict__ Y,
    const int* __restrict__ code, const float* __restrict__ pw,
    const int* __restrict__ basep,
    float* __restrict__ out)
{
    int t = blockIdx.x;
    int c0 = code[t * 2], c1 = code[t * 2 + 1];
    float p0 = pw[t * 2], p1 = pw[t * 2 + 1];
    size_t r0 = (size_t)(basep[c0 >> 13] + (c0 & 0x1FFF)) * DIM;
    size_t r1 = (size_t)(basep[c1 >> 13] + (c1 & 0x1FFF)) * DIM;
    int d = threadIdx.x * 4;
    u16x4 a = *(const u16x4*)(Y + r0 + d);
    u16x4 b = *(const u16x4*)(Y + r1 + d);
    float4 o;
    o.x = p0 * bits2f(a[0]) + p1 * bits2f(b[0]);
    o.y = p0 * bits2f(a[1]) + p1 * bits2f(b[1]);
    o.z = p0 * bits2f(a[2]) + p1 * bits2f(b[2]);
    o.w = p0 * bits2f(a[3]) + p1 * bits2f(b[3]);
    *(float4*)(out + (size_t)t * DIM + d) = o;
}

// ======================= launch =======================
extern "C" void kernel_launch(void* const* d_in, const int* in_sizes, int n_in,
                              void* d_out, int out_size, void* d_ws, size_t ws_size,
                              hipStream_t stream)
{
    const float* x    = (const float*)d_in[0];
    const float* gate = (const float*)d_in[1];
    const float* w1   = (const float*)d_in[2];
    const float* w2   = (const float*)d_in[3];
    float* out = (float*)d_out;

    char* ws = (char*)d_ws;
    int*   counts   = (int*)(ws + 0);
    int*   basep    = (int*)(ws + 256);
    int*   epack    = (int*)(ws + 1024);                      // 32 KB
    int*   H0       = (int*)(ws + 1024 + 32768);
    int*   H1       = (int*)(ws + 1024 + 40960);
    float* Pblk     = (float*)(ws + 1024 + 49152);
    int*   bbL      = (int*)(ws + 1024 + 57344);
    int*   tok_list = (int*)(ws + 131072);                    // 256 KB
    int*   code     = (int*)(ws + 131072 + 262144);           // 64 KB
    float* pw       = (float*)(ws + 131072 + 262144 + 65536); // 64 KB
    // big buffers (all bf16):
    //   [1MB, 33MB)   w1t
    //   [33MB, 65MB)  w2t
    //   [65MB,129MB)  hidden
    //   [129MB,161MB) xb (first 16MB; dead after GEMM1) -> reused as Y
    unsigned short* w1t    = (unsigned short*)(ws + (1 << 20));
    unsigned short* w2t    = (unsigned short*)(ws + (1 << 20) + 33554432);
    unsigned short* hidden = (unsigned short*)(ws + (1 << 20) + 67108864);
    unsigned short* xb     = (unsigned short*)(ws + (1 << 20) + 134217728);
    unsigned short* Y      = xb;   // GEMM2 output (xb dead by then)

    fused_pre_k<<<RB + 8192, 256, 0, stream>>>(x, gate, w1, w2, epack, pw, xb,
                                               H0, H1, Pblk, w1t, w2t);
    scan_k<<<1, 256, 0, stream>>>(H0, H1, Pblk, bbL, counts, basep, out + (size_t)N_TOK * DIM);
    scatter_k<<<64, 256, 0, stream>>>(epack, bbL, tok_list, code);
    moe_gemm<true, true, DIM / 64><<<dim3(HID / 128, 64, NEXP), 256, 0, stream>>>(
        xb, w1t, hidden, counts, basep, tok_list, HID);
    moe_gemm<false, false, HID / 64><<<dim3(DIM / 128, 64, NEXP), 256, 0, stream>>>(
        hidden, w2t, Y, counts, basep, tok_list, DIM);
    combine_k<<<N_TOK, 256, 0, stream>>>(Y, code, pw, basep, out);
}